// Round 10
// baseline (370.097 us; speedup 1.0000x reference)
//
#include <hip/hip_runtime.h>
#include <math.h>

#define D_MODEL 768
#define NHEAD 12
#define HEAD_DIM 64
#define SEQ_B 2
#define SEQ_L 2048
#define M_ROWS (SEQ_B * SEQ_L)

using f16 = _Float16;
typedef _Float16 f16x8 __attribute__((ext_vector_type(8)));
typedef float f32x4 __attribute__((ext_vector_type(4)));

// ---------------------------------------------------------------------------
// Fused prep: four fp32 [K][N] -> fp16 [N][K] transposes PLUS LN1, one launch.
// ---------------------------------------------------------------------------
#define T0 1728                 // (2304/32)*(768/32)
#define T1 576                  // (768/32)*(768/32)
#define T2 2304                 // (3072/32)*(768/32)
#define T3 2304                 // (768/32)*(3072/32)
#define TC0 (T0)
#define TC1 (T0 + T1)
#define TC2 (T0 + T1 + T2)
#define TC3 (T0 + T1 + T2 + T3)        // 6912 transpose tiles
#define PREP_BLOCKS (TC3 + M_ROWS)     // + 4096 LN1 rows

__global__ __launch_bounds__(256) void prep5_kernel(
    const float* __restrict__ s0, f16* __restrict__ d0,
    const float* __restrict__ s1, f16* __restrict__ d1,
    const float* __restrict__ s2, f16* __restrict__ d2,
    const float* __restrict__ s3, f16* __restrict__ d3,
    const float* __restrict__ x, const float* __restrict__ g,
    const float* __restrict__ be, f16* __restrict__ y16) {
    __shared__ float tile[32][33];
    __shared__ float red_s[4], red_ss[4];
    const int bid = blockIdx.x;
    const int tid = threadIdx.x;

    if (bid >= TC3) {  // ---- LN1 row ----
        const int row = bid - TC3;
        const float* xr = x + (size_t)row * D_MODEL;
        float v[3];
        float s = 0.f, ss = 0.f;
#pragma unroll
        for (int j = 0; j < 3; ++j) {
            v[j] = xr[tid + j * 256];
            s += v[j];
            ss += v[j] * v[j];
        }
#pragma unroll
        for (int off = 1; off < 64; off <<= 1) {
            s += __shfl_xor(s, off, 64);
            ss += __shfl_xor(ss, off, 64);
        }
        const int wid = tid >> 6;
        if ((tid & 63) == 0) { red_s[wid] = s; red_ss[wid] = ss; }
        __syncthreads();
        s = red_s[0] + red_s[1] + red_s[2] + red_s[3];
        ss = red_ss[0] + red_ss[1] + red_ss[2] + red_ss[3];
        const float mean = s * (1.f / D_MODEL);
        const float var = ss * (1.f / D_MODEL) - mean * mean;
        const float rstd = rsqrtf(var + 1e-5f);
#pragma unroll
        for (int j = 0; j < 3; ++j) {
            const int c = tid + j * 256;
            y16[(size_t)row * D_MODEL + c] = (f16)((v[j] - mean) * rstd * g[c] + be[c]);
        }
        return;
    }

    // ---- transpose tile ----
    const float* in;
    f16* out;
    int t, K, N;
    if (bid < TC0)      { in = s0; out = d0; t = bid;       K = 768;  N = 2304; }
    else if (bid < TC1) { in = s1; out = d1; t = bid - TC0; K = 768;  N = 768;  }
    else if (bid < TC2) { in = s2; out = d2; t = bid - TC1; K = 768;  N = 3072; }
    else                { in = s3; out = d3; t = bid - TC2; K = 3072; N = 768;  }
    const int tiles_x = N >> 5;
    const int n0 = (t % tiles_x) * 32;
    const int k0 = (t / tiles_x) * 32;
#pragma unroll
    for (int i = 0; i < 4; ++i) {
        const int idx = tid + i * 256;
        const int r = idx >> 5, c = idx & 31;
        tile[r][c] = in[(size_t)(k0 + r) * N + n0 + c];
    }
    __syncthreads();
#pragma unroll
    for (int i = 0; i < 4; ++i) {
        const int idx = tid + i * 256;
        const int r = idx >> 5, c = idx & 31;
        out[(size_t)(n0 + r) * K + k0 + c] = (f16)tile[c][r];
    }
}

// ---------------------------------------------------------------------------
// LayerNorm: one block per row (768 cols), 256 threads, 3 elems/thread.
// ---------------------------------------------------------------------------
template <int BOTH>
__global__ __launch_bounds__(256) void ln_kernel(const float* __restrict__ in,
                                                 const float* __restrict__ gamma,
                                                 const float* __restrict__ beta,
                                                 float* __restrict__ out32,
                                                 f16* __restrict__ out16) {
    const int row = blockIdx.x;
    const float* x = in + (size_t)row * D_MODEL;
    float v[3];
    float s = 0.f, ss = 0.f;
#pragma unroll
    for (int j = 0; j < 3; ++j) {
        v[j] = x[threadIdx.x + j * 256];
        s += v[j];
        ss += v[j] * v[j];
    }
#pragma unroll
    for (int off = 1; off < 64; off <<= 1) {
        s += __shfl_xor(s, off, 64);
        ss += __shfl_xor(ss, off, 64);
    }
    __shared__ float red_s[4], red_ss[4];
    const int wid = threadIdx.x >> 6;
    if ((threadIdx.x & 63) == 0) { red_s[wid] = s; red_ss[wid] = ss; }
    __syncthreads();
    s = red_s[0] + red_s[1] + red_s[2] + red_s[3];
    ss = red_ss[0] + red_ss[1] + red_ss[2] + red_ss[3];
    const float mean = s * (1.f / D_MODEL);
    const float var = ss * (1.f / D_MODEL) - mean * mean;
    const float rstd = rsqrtf(var + 1e-5f);
#pragma unroll
    for (int j = 0; j < 3; ++j) {
        const int c = threadIdx.x + j * 256;
        const float y = (v[j] - mean) * rstd * gamma[c] + beta[c];
        if (BOTH) out32[(size_t)row * D_MODEL + c] = y;
        out16[(size_t)row * D_MODEL + c] = (f16)y;
    }
}

// ---------------------------------------------------------------------------
// MFMA fp16 GEMM: out[M,N] = A[M,K](f16) @ BT[N,K](f16)^T + bias
// NW waves as WM x (NW/WM); per-wave FM x FN 16x16 frags.
// BM = WM*FM*16, BN = (NW/WM)*FN*16, BK=32. Double-buffered LDS, ONE barrier
// per K-step; global prefetch stays in flight across the MFMA phase.
// ---------------------------------------------------------------------------
__device__ __forceinline__ float gelu_exact(float x) {
    return 0.5f * x * (1.f + erff(x * 0.70710678118654752440f));
}

template <int ACT, int RES, int OUTH, int WM, int FM, int FN, int NW>
__global__ __launch_bounds__(NW * 64) void hgemm_kernel(
    const f16* __restrict__ A, const f16* __restrict__ BT,
    const float* __restrict__ bias, const float* __restrict__ res,
    void* __restrict__ outp, int N, int K) {
    constexpr int WN = NW / WM;
    constexpr int BM = WM * FM * 16;
    constexpr int BN = WN * FN * 16;
    constexpr int NTHR = NW * 64;
    constexpr int NLD = (BM + BN) * 4 / NTHR;  // f16x8 chunks per thread
    static_assert((BM + BN) * 4 == NLD * NTHR, "loader must divide evenly");
    __shared__ f16 As[2][BM * 40];  // [m][k], row stride 40 halves (80 B)
    __shared__ f16 Bs[2][BN * 40];  // [n][k]
    const int tid = threadIdx.x;
    const int wave = tid >> 6;
    const int lane = tid & 63;
    const int lg = lane >> 4;   // lane group 0..3
    const int lr = lane & 15;   // lane row 0..15
    const int wm = wave / WN;
    const int wn = wave % WN;

    // XCD-aware swizzle (grids are divisible by 8 -> bijective radix remap).
    const int nwg = gridDim.x * gridDim.y;
    int id = blockIdx.y * gridDim.x + blockIdx.x;
    id = (id & 7) * (nwg >> 3) + (id >> 3);
    const int m0 = (id / gridDim.x) * BM;
    const int n0 = (id % gridDim.x) * BN;

    f32x4 acc[FM][FN];
#pragma unroll
    for (int mi = 0; mi < FM; ++mi)
#pragma unroll
        for (int ni = 0; ni < FN; ++ni) acc[mi][ni] = (f32x4){0.f, 0.f, 0.f, 0.f};

    f16x8 regs[NLD];
    auto load_tile = [&](int k0) {
#pragma unroll
        for (int i = 0; i < NLD; ++i) {
            const int c = tid + i * NTHR;
            const int row = c >> 2;
            const int off = (c & 3) * 8;
            const f16* src = (row < BM)
                                 ? A + (size_t)(m0 + row) * K + k0 + off
                                 : BT + (size_t)(n0 + row - BM) * K + k0 + off;
            regs[i] = *(const f16x8*)src;
        }
    };
    auto write_tile = [&](int p) {
#pragma unroll
        for (int i = 0; i < NLD; ++i) {
            const int c = tid + i * NTHR;
            const int row = c >> 2;
            const int off = (c & 3) * 8;
            if (row < BM)
                *(f16x8*)(&As[p][row * 40 + off]) = regs[i];
            else
                *(f16x8*)(&Bs[p][(row - BM) * 40 + off]) = regs[i];
        }
    };

    load_tile(0);
    int p = 0;
    for (int k0 = 0; k0 < K; k0 += 32) {
        write_tile(p);
        __syncthreads();
        if (k0 + 32 < K) load_tile(k0 + 32);  // in flight across MFMA phase
        f16x8 af[FM], bf[FN];
#pragma unroll
        for (int mi = 0; mi < FM; ++mi)
            af[mi] = *(const f16x8*)(&As[p][(wm * FM * 16 + mi * 16 + lr) * 40 + lg * 8]);
#pragma unroll
        for (int ni = 0; ni < FN; ++ni)
            bf[ni] = *(const f16x8*)(&Bs[p][(wn * FN * 16 + ni * 16 + lr) * 40 + lg * 8]);
#pragma unroll
        for (int mi = 0; mi < FM; ++mi)
#pragma unroll
            for (int ni = 0; ni < FN; ++ni)
                acc[mi][ni] = __builtin_amdgcn_mfma_f32_16x16x32_f16(
                    af[mi], bf[ni], acc[mi][ni], 0, 0, 0);
        p ^= 1;
    }

    // Epilogue. D layout: col = lane&15, row = (lane>>4)*4 + r (HW-verified).
#pragma unroll
    for (int mi = 0; mi < FM; ++mi) {
#pragma unroll
        for (int ni = 0; ni < FN; ++ni) {
            const int gcol = n0 + wn * FN * 16 + ni * 16 + lr;
            const float bb = bias[gcol];
#pragma unroll
            for (int r = 0; r < 4; ++r) {
                const int grow = m0 + wm * FM * 16 + mi * 16 + lg * 4 + r;
                float vv = acc[mi][ni][r] + bb;
                if (ACT == 1) vv = gelu_exact(vv);
                if (RES == 1) vv += res[(size_t)grow * N + gcol];
                if (OUTH == 1)
                    ((f16*)outp)[(size_t)grow * N + gcol] = (f16)vv;
                else
                    ((float*)outp)[(size_t)grow * N + gcol] = vv;
            }
        }
    }
}

// ---------------------------------------------------------------------------
// MFMA fp16 flash attention (causal). qkv fp16 rows of 2304 = [3][12][64].
// 256 thr = 4 waves; 64 q-rows per block; KV tiles of 64. Double-buffered
// K/V LDS, one barrier per tile, reg prefetch (T14). Vt kpos-slot XOR
// swizzle -> transposed write is 2 lanes/bank (free); read applies same XOR.
// Mask hoisted to diagonal tile (provably no-op for kt<qt); T13 defer-max.
// ---------------------------------------------------------------------------
__global__ __launch_bounds__(256) void attn_kernel(const f16* __restrict__ qkv,
                                                   f16* __restrict__ ctx) {
    __shared__ f16 Ks[2][64 * 72];    // [kpos][d]   (row stride 72)
    __shared__ f16 Vt[2][64 * 72];    // [d][kpos^swz(d)]
    __shared__ f16 Ps[4][16 * 72];    // per wave: [q16][kpos64]

    const int tid = threadIdx.x;
    const int wave = tid >> 6;
    const int lane = tid & 63;
    const int lg = lane >> 4;
    const int lr = lane & 15;
    const int qt = gridDim.x - 1 - blockIdx.x;  // heavy blocks first
    const int bh = blockIdx.y;
    const int b = bh / NHEAD;
    const int h = bh % NHEAD;
    const int q0 = qt * 64;
    const size_t baseb = (size_t)b * SEQ_L * 2304;
    const int ko = 768 + h * 64;
    const int vo = 1536 + h * 64;

    // Q fragments in registers (pre-scaled by 1/sqrt(d)).
    f16x8 qf[2];
    {
        const size_t qrow = baseb + (size_t)(q0 + wave * 16 + lr) * 2304 + h * 64;
#pragma unroll
        for (int kc = 0; kc < 2; ++kc) {
            qf[kc] = *(const f16x8*)(qkv + qrow + kc * 32 + lg * 8);
            qf[kc] *= (_Float16)0.125f;
        }
    }

    f16x8 kreg[2], vreg[2];
    auto load_kv = [&](int kt) {
#pragma unroll
        for (int i = 0; i < 2; ++i) {
            const int c = tid + i * 256;   // 0..511
            const int r = c >> 3;          // kpos 0..63
            const int off = (c & 7) * 8;   // d 0..56
            const size_t gbase = baseb + (size_t)(kt * 64 + r) * 2304;
            kreg[i] = *(const f16x8*)(qkv + gbase + ko + off);
            vreg[i] = *(const f16x8*)(qkv + gbase + vo + off);
        }
    };
    auto write_kv = [&](int p) {
#pragma unroll
        for (int i = 0; i < 2; ++i) {
            const int c = tid + i * 256;
            const int r = c >> 3;          // kpos
            const int off = (c & 7) * 8;   // d base (d>>3 == c&7 for j<8)
            *(f16x8*)(&Ks[p][r * 72 + off]) = kreg[i];
            const int rs = r ^ ((c & 7) << 3);  // swizzled kpos slot
#pragma unroll
            for (int j = 0; j < 8; ++j) Vt[p][(off + j) * 72 + rs] = vreg[i][j];
        }
    };

    f32x4 o[4];
#pragma unroll
    for (int di = 0; di < 4; ++di) o[di] = (f32x4){0.f, 0.f, 0.f, 0.f};
    float m_[4], l_[4];
#pragma unroll
    for (int r = 0; r < 4; ++r) { m_[r] = -1e30f; l_[r] = 0.f; }

    load_kv(0);
    int p = 0;
    for (int kt = 0; kt <= qt; ++kt) {
        write_kv(p);
        __syncthreads();
        if (kt < qt) load_kv(kt + 1);  // in flight across compute

        // S = Q K^T : A=Q (regs), B-frag = K rows from Ks.
        f32x4 s[4];
        __builtin_amdgcn_s_setprio(1);
#pragma unroll
        for (int ni = 0; ni < 4; ++ni) {
            const f16x8 kf0 = *(const f16x8*)(&Ks[p][(ni * 16 + lr) * 72 + lg * 8]);
            const f16x8 kf1 = *(const f16x8*)(&Ks[p][(ni * 16 + lr) * 72 + 32 + lg * 8]);
            s[ni] = __builtin_amdgcn_mfma_f32_16x16x32_f16(
                qf[0], kf0, (f32x4){0.f, 0.f, 0.f, 0.f}, 0, 0, 0);
            s[ni] = __builtin_amdgcn_mfma_f32_16x16x32_f16(qf[1], kf1, s[ni], 0, 0, 0);
        }
        __builtin_amdgcn_s_setprio(0);

        // Causal mask: can only fire on the diagonal tile (kt<qt => kg<qg).
        if (kt == qt) {
#pragma unroll
            for (int r = 0; r < 4; ++r) {
                const int qg = q0 + wave * 16 + lg * 4 + r;
#pragma unroll
                for (int ni = 0; ni < 4; ++ni) {
                    const int kg = kt * 64 + ni * 16 + lr;
                    if (kg > qg) s[ni][r] = -1e30f;
                }
            }
        }

        // Online softmax with T13 defer-max (THR=8): keep old max unless the
        // new tile max exceeds it by >8; P then bounded by e^8 (f16-safe).
        float fsc[4];
#pragma unroll
        for (int r = 0; r < 4; ++r) {
            float mx = fmaxf(fmaxf(s[0][r], s[1][r]), fmaxf(s[2][r], s[3][r]));
#pragma unroll
            for (int off = 1; off < 16; off <<= 1) mx = fmaxf(mx, __shfl_xor(mx, off, 64));
            if (mx > m_[r] + 8.f) {
                fsc[r] = __expf(m_[r] - mx);
                m_[r] = mx;
            } else {
                fsc[r] = 1.f;
            }
            float rs = 0.f;
#pragma unroll
            for (int ni = 0; ni < 4; ++ni) {
                const float pv = __expf(s[ni][r] - m_[r]);
                s[ni][r] = pv;
                rs += pv;
            }
#pragma unroll
            for (int off = 1; off < 16; off <<= 1) rs += __shfl_xor(rs, off, 64);
            l_[r] = l_[r] * fsc[r] + rs;
            if (fsc[r] != 1.f) {
#pragma unroll
                for (int di = 0; di < 4; ++di) o[di][r] *= fsc[r];
            }
        }
        // P -> per-wave LDS buffer: Ps[q16][kpos64]. No barrier needed.
        // (Known 4-way write conflict; unfixable without T12 restructure.)
#pragma unroll
        for (int ni = 0; ni < 4; ++ni)
#pragma unroll
            for (int r = 0; r < 4; ++r)
                Ps[wave][(lg * 4 + r) * 72 + ni * 16 + lr] = (f16)s[ni][r];

        // O += P V : A=P (m=q=lr), B=V^T rows from swizzled Vt (n=d=lr).
        __builtin_amdgcn_s_setprio(1);
#pragma unroll
        for (int kc = 0; kc < 2; ++kc) {
            const f16x8 pf = *(const f16x8*)(&Ps[wave][lr * 72 + kc * 32 + lg * 8]);
#pragma unroll
            for (int di = 0; di < 4; ++di) {
                const int vrow = di * 16 + lr;
                const int vsw = ((kc * 4 + lg) ^ (vrow >> 3)) << 3;
                const f16x8 vf = *(const f16x8*)(&Vt[p][vrow * 72 + vsw]);
                o[di] = __builtin_amdgcn_mfma_f32_16x16x32_f16(pf, vf, o[di], 0, 0, 0);
            }
        }
        __builtin_amdgcn_s_setprio(0);
        p ^= 1;
    }

    // Epilogue: normalize, store ctx fp16 [B*L][768].
#pragma unroll
    for (int r = 0; r < 4; ++r) {
        const float inv = 1.f / l_[r];
        const size_t grow = (size_t)(b * SEQ_L + q0 + wave * 16 + lg * 4 + r);
#pragma unroll
        for (int di = 0; di < 4; ++di)
            ctx[grow * D_MODEL + h * 64 + di * 16 + lr] = (f16)(o[di][r] * inv);
    }
}

// ---------------------------------------------------------------------------
extern "C" void kernel_launch(void* const* d_in, const int* in_sizes, int n_in,
                              void* d_out, int out_size, void* d_ws, size_t ws_size,
                              hipStream_t stream) {
    const float* x = (const float*)d_in[0];
    const float* qkv_w = (const float*)d_in[1];
    const float* qkv_b = (const float*)d_in[2];
    const float* out_w = (const float*)d_in[3];
    const float* out_b = (const float*)d_in[4];
    const float* ln1_g = (const float*)d_in[5];
    const float* ln1_b = (const float*)d_in[6];
    const float* ln2_g = (const float*)d_in[7];
    const float* ln2_b = (const float*)d_in[8];
    const float* ffn_w1 = (const float*)d_in[9];
    const float* ffn_b1 = (const float*)d_in[10];
    const float* ffn_w2 = (const float*)d_in[11];
    const float* ffn_b2 = (const float*)d_in[12];
    float* out = (float*)d_out;

    // Workspace layout with aliasing; ~77 MB total.
    const size_t M = M_ROWS;
    f16* wqkvT = (f16*)d_ws;                          // [2304][768]
    f16* woutT = wqkvT + (size_t)2304 * 768;          // [768][768]
    f16* w1T = woutT + (size_t)768 * 768;             // [3072][768]
    f16* w2T = w1T + (size_t)3072 * 768;              // [768][3072]
    f16* a1_ctx = w2T + (size_t)768 * 3072;           // [M][768]  A1 then ctx
    f16* qkvh = a1_ctx + M * 768;                     // [M][2304] steps 2-3
    float* proj32 = (float*)qkvh;                     // [M][768] f32 (alias, 4-5)
    f16* ln2h = qkvh + M * 1536;                      // [M][768] f16 (alias, 5-6)
    float* ln2_32 = (float*)(qkvh + M * 2304);        // [M][768] f32 (5-7)
    f16* hh = (f16*)(ln2_32 + M * 768);               // [M][3072] (6-7)

    // 0+1. Weight transposes + LN1 fused in one launch.
    prep5_kernel<<<PREP_BLOCKS, 256, 0, stream>>>(qkv_w, wqkvT, out_w, woutT,
                                                  ffn_w1, w1T, ffn_w2, w2T,
                                                  x, ln1_g, ln1_b, a1_ctx);

    // 2. QKV GEMM -> fp16 [M][2304]  (64x128 tiles, 2-wave, 1152 blocks = 4.5/CU)
    hgemm_kernel<0, 0, 1, 1, 4, 4, 2>
        <<<dim3(2304 / 128, M_ROWS / 64), 128, 0, stream>>>(
            a1_ctx, wqkvT, qkv_b, nullptr, qkvh, 2304, 768);
    // 3. Flash attention -> ctx fp16 (overwrites a1_ctx)
    attn_kernel<<<dim3(SEQ_L / 64, SEQ_B * NHEAD), 256, 0, stream>>>(qkvh, a1_ctx);
    // 4. Output projection -> fp32    (64x64 tiles, 2-wave, 768 blocks = 3/CU)
    hgemm_kernel<0, 0, 0, 1, 4, 2, 2>
        <<<dim3(768 / 64, M_ROWS / 64), 128, 0, stream>>>(
            a1_ctx, woutT, out_b, nullptr, proj32, 768, 768);
    // 5. LN2 -> fp32 + fp16
    ln_kernel<1><<<M_ROWS, 256, 0, stream>>>(proj32, ln2_g, ln2_b, ln2_32, ln2h);
    // 6. FFN1 + exact GELU -> fp16 [M][3072]   (128x128 tiles, 768 blocks = 3/CU)
    hgemm_kernel<1, 0, 1, 2, 4, 4, 4>
        <<<dim3(3072 / 128, M_ROWS / 128), 256, 0, stream>>>(
            ln2h, w1T, ffn_b1, nullptr, hh, 3072, 768);
    // 7. FFN2 + bias + residual(ln2_32) -> fp32 out (64x64 tiles, 768 blocks = 3/CU)
    hgemm_kernel<0, 1, 0, 1, 4, 2, 2>
        <<<dim3(768 / 64, M_ROWS / 64), 128, 0, stream>>>(
            hh, w2T, ffn_b2, ln2_32, out, 768, 3072);
}